// Round 2
// baseline (175.695 us; speedup 1.0000x reference)
//
#include <hip/hip_runtime.h>
#include <math.h>

// Round 4b: scalarize wave-uniform control (readfirstlane) + incremental
// SALU row pointers + unroll-4 to rename ring buffers and pipeline bperms.
// Fix vs R4: output base pointer must not be const.
#define IMW 512
#define SEG 32
#define NSEG (512/SEG)     // 16
#define NSTRIP 10          // 10*52 = 520 >= 512
#define OUTW 52

__device__ __forceinline__ int reflect512(int i) {   // valid for i in [-511,1022]
    int a = i < 0 ? -i : i;
    int b = 1022 - a;
    return a < b ? a : b;
}
__device__ __forceinline__ float bperm(int a4, float v) {
    return __int_as_float(__builtin_amdgcn_ds_bpermute(a4, __float_as_int(v)));
}

__global__ __launch_bounds__(256)
void canny_pipe(const float* __restrict__ x, float* __restrict__ out) {
    const int lane  = threadIdx.x & 63;
    // unit is wave-uniform: force it into SGPRs so img/strip/seg/Y0, base
    // pointers, loop bounds and row conditionals all become scalar.
    const int unit  = __builtin_amdgcn_readfirstlane(
                          (int)(blockIdx.x * 4 + (threadIdx.x >> 6)));
    const int img   = unit / (NSTRIP * NSEG);
    const int rem   = unit - img * (NSTRIP * NSEG);
    const int strip = rem / NSEG;
    const int seg   = rem - strip * NSEG;
    const int Y0 = seg * SEG, Y1 = Y0 + SEG;
    const int x0 = strip * OUTW - 6;
    const int xv = x0 + lane;                  // virtual x (may be OOB)
    const int xr = reflect512(xv);             // load column (reflect pad in x)
    const bool inimg  = (xv >= 0) && (xv < IMW);
    const bool stlane = (lane >= 6) && (lane < 58) && (xv < IMW);
    const int l4  = lane << 2;
    // sobel h-pass clamped-neighbor lanes (edge clamp in x)
    const int aL4 = (min(max(xv - 1, 0), 511) - x0) << 2;
    const int aR4 = (min(max(xv + 1, 0), 511) - x0) << 2;

    // scalar base pointers, advanced incrementally (reflect walks +-1 row/iter)
    const float* base = x + (size_t)img * 3 * IMW * IMW;
    const int r0 = reflect512(Y0 - 6);
    const float* b0 = base + (size_t)r0 * IMW;              // channel 0, row r0
    const float* b1 = b0 + (size_t)IMW * IMW;               // channel 1
    const float* b2 = b0 + (size_t)2 * IMW * IMW;           // channel 2
    float* ob = out + (size_t)img * IMW * IMW;

    const float K0 = 0.054488684549643f, K1 = 0.244201342003233f, K2 = 0.402619946931554f;

    // ring buffers (shift registers); index grows with row
    float hb0=0,hb1=0,hb2=0,hb3=0,hb4=0;          // h-blurred gray, rows v-4..v
    float hx0=0,hx1=0,hx2=0, hy0=0,hy1=0,hy2=0;   // sobel h-passes, rows v-4..v-2
    float mg0=0,mg1=0,mg2=0;                      // magnitude, rows v-5..v-3
    int   ax0=0, ax1=0;                           // axis, rows v-4, v-3
    float cm0=0,cm1=0,cm2=0,cm3=0,cm4=0;          // col-max of msk, rows v-8..v-4

    // prefetch gray row for v = Y0-6
    float p0 = b0[xr];
    float p1 = b1[xr];
    float p2 = b2[xr];

    #pragma unroll 4
    for (int v = Y0 - 6; v <= Y1 + 5; ++v) {
        // ---- gray row v (channel-reversed weights) + prefetch row v+1
        float gray = 0.299f * p2 + 0.587f * p1 + 0.114f * p0;
        // reflected row index of v+1 differs from that of v by exactly +-1:
        // +1 while 0 <= v <= 510, else -1 (covers both top and bottom reflect)
        const int d = ((unsigned)v <= 510u) ? IMW : -IMW;   // scalar
        b0 += d; b1 += d; b2 += d;
        p0 = b0[xr];
        p1 = b1[xr];
        p2 = b2[xr];

        // ---- h-blur (x reflect already baked into per-lane loads)
        float gl1 = bperm(l4 - 4, gray), gl2 = bperm(l4 - 8, gray);
        float gr1 = bperm(l4 + 4, gray), gr2 = bperm(l4 + 8, gray);
        hb0 = hb1; hb1 = hb2; hb2 = hb3; hb3 = hb4;
        hb4 = K0 * (gl2 + gr2) + K1 * (gl1 + gr1) + K2 * gray;

        // ---- v-blur -> blurred row v-2; sobel h-passes (edge-clamped x)
        float blur = K0 * (hb0 + hb4) + K1 * (hb1 + hb3) + K2 * hb2;
        float bl = bperm(aL4, blur), br = bperm(aR4, blur);
        hx0 = hx1; hx1 = hx2; hx2 = br - bl;
        hy0 = hy1; hy1 = hy2; hy2 = bl + 2.f * blur + br;

        // ---- sobel v-pass + mag + axis, row g = v-3 (edge-clamped y)
        const int g = v - 3;
        float hxa = (g == 0)   ? hx1 : hx0;
        float hxc = (g == 511) ? hx1 : hx2;
        float hya = (g == 0)   ? hy1 : hy0;
        float hyc = (g == 511) ? hy1 : hy2;
        float gxv = (hxa + 2.f * hx1 + hxc) * 0.125f;
        float gyv = (hyc - hya) * 0.125f;
        float mag = sqrtf(gxv * gxv + gyv * gyv + 1e-6f);
        float axm = fabsf(gxv), aym = fabsf(gyv);
        int axis;
        if (aym <= 0.41421356237309515f * axm)      axis = 0;  // (0,+-1)
        else if (aym >= 2.4142135623730951f * axm)  axis = 2;  // (+-1,0)
        else axis = ((gxv >= 0.f) == (gyv >= 0.f)) ? 1 : 3;    // diagonals
        mg0 = mg1; mg1 = mg2; mg2 = inimg ? mag : 0.f;
        ax0 = ax1; ax1 = axis;

        // ---- NMS + mask, row m = v-4 (zero-pad y and x via zeroed lanes)
        const int m = v - 4;
        float magm = (m == 0)   ? 0.f : mg0;   // row m-1
        float magc = mg1;                      // row m
        float magp = (m == 511) ? 0.f : mg2;   // row m+1
        // gather neighbor values per source row, select by MY axis afterwards
        float gcp = bperm(l4 + 4, magc), gcm = bperm(l4 - 4, magc);
        float gpp = bperm(l4 + 4, magp), gpm = bperm(l4 - 4, magp);
        float gmm = bperm(l4 - 4, magm), gmp = bperm(l4 + 4, magm);
        const int dd = ax0;
        float mp = (dd == 0) ? gcp : (dd == 1) ? gpp : (dd == 2) ? magp : gpm;
        float mn = (dd == 0) ? gcm : (dd == 1) ? gmm : (dd == 2) ? magm : gmp;
        float msk = (inimg && fminf(magc - mp, magc - mn) > 0.f) ? magc : 0.f;

        // ---- horizontal 5-max -> colmax row m
        float s1 = fmaxf(bperm(l4 - 4, msk), bperm(l4 + 4, msk));
        float s2 = fmaxf(bperm(l4 - 8, msk), bperm(l4 + 8, msk));
        cm0 = cm1; cm1 = cm2; cm2 = cm3; cm3 = cm4;
        cm4 = fmaxf(fmaxf(s1, s2), msk);

        // ---- vertical 5-max -> out row y = v-6 (zero-pad y; msk >= 0)
        const int y = v - 6;
        if (y >= Y0) {
            float c0 = (y >= 2)   ? cm0 : 0.f;
            float c1 = (y >= 1)   ? cm1 : 0.f;
            float c3 = (y <= 510) ? cm3 : 0.f;
            float c4 = (y <= 509) ? cm4 : 0.f;
            float val = fmaxf(fmaxf(fmaxf(c0, c1), fmaxf(cm2, c3)), c4);
            if (stlane) ob[(size_t)y * IMW + xv] = val;
        }
    }
}

extern "C" void kernel_launch(void* const* d_in, const int* in_sizes, int n_in,
                              void* d_out, int out_size, void* d_ws, size_t ws_size,
                              hipStream_t stream) {
    const float* x = (const float*)d_in[0];
    float* out = (float*)d_out;
    const int units = 32 * NSTRIP * NSEG;   // 5120 waves
    dim3 grid(units / 4);                   // 4 waves per 256-thread block
    canny_pipe<<<grid, 256, 0, stream>>>(x, out);
}